// Round 10
// baseline (70.686 us; speedup 1.0000x reference)
//
#include <hip/hip_runtime.h>
#include <climits>

// Problem constants: B=8, C=8, H=512, W=512
#define HWSZ 262144      // H*W
#define CHWSZ 2097152    // C*H*W

typedef int i32x4 __attribute__((ext_vector_type(4)));     // i8 MFMA frag / acc
typedef float f4 __attribute__((ext_vector_type(4)));      // component-indexable float4

// ---------------- argmax: cached loads, u8 labels, int row-norms, init, counter ------
// Ledger (R1-R9): beyond-local-L2 read service caps ~3.2 TB/s (HBM or L3, any
// structure; NT reaches 3.4 but poisons downstream +21us). 128 MB irreducible
// input read -> ~40us floor; replay argmax = 41.5-42us = ~96% of floor.
// Labels now int8 (values 0..7): all distance math exact in i32, dist bytes halved.
__global__ __launch_bounds__(256) void hd_argmax(const float* __restrict__ logits,
                                                 const float* __restrict__ target,
                                                 unsigned char* __restrict__ lxb,
                                                 unsigned char* __restrict__ tyb,
                                                 int* __restrict__ x2,
                                                 int* __restrict__ y2,
                                                 int* __restrict__ rowmin,
                                                 int* __restrict__ colmin,
                                                 int* __restrict__ counter) {
    int gid = blockIdx.x * 256 + threadIdx.x;
    if (gid < 4096) {            // fused init (dist runs later on the same stream)
        rowmin[gid] = INT_MAX;
        colmin[gid] = INT_MAX;
    }
    if (gid == 4096) counter[0] = 0;          // reset fused-final handshake each call
    int t = gid;                              // 0 .. 256K-1
    int p = t << 3;                           // pixel index (8 px per thread)
    int b = p >> 18;                          // / (H*W)
    int off = p & (HWSZ - 1);
    int l = threadIdx.x & 63;
    int row = p >> 9;                         // global row 0..4095 (same for whole wave)

    const f4* L = (const f4*)(logits + (size_t)b * CHWSZ + off);
    const f4* T = (const f4*)(target + (size_t)b * CHWSZ + off);

    // ---- logits ----
    {
        f4 v[16];
#pragma unroll
        for (int c = 0; c < 8; ++c) {
            v[2 * c]     = L[c * (HWSZ / 4)];
            v[2 * c + 1] = L[c * (HWSZ / 4) + 1];
        }
        unsigned long long pk = 0;
        int s = 0;
#pragma unroll
        for (int half = 0; half < 2; ++half) {
#pragma unroll
            for (int j = 0; j < 4; ++j) {
                float bv = v[half][j];
                int bi = 0;
#pragma unroll
                for (int c = 1; c < 8; ++c) {
                    float x = v[2 * c + half][j];
                    bool g = x > bv;            // strict >: first-max, matches jnp.argmax
                    bv = g ? x : bv;
                    bi = g ? c : bi;
                }
                pk |= (unsigned long long)bi << (8 * (half * 4 + j));
                s += bi * bi;
            }
        }
        *(unsigned long long*)(lxb + p) = pk;   // 8 px -> 8 bytes
#pragma unroll
        for (int o = 32; o > 0; o >>= 1) s += __shfl_xor(s, o, 64);
        if (l == 0) x2[row] = s;
    }
    // ---- target ----
    {
        f4 w[16];
#pragma unroll
        for (int c = 0; c < 8; ++c) {
            w[2 * c]     = T[c * (HWSZ / 4)];
            w[2 * c + 1] = T[c * (HWSZ / 4) + 1];
        }
        unsigned long long pk = 0;
        int s = 0;
#pragma unroll
        for (int half = 0; half < 2; ++half) {
#pragma unroll
            for (int j = 0; j < 4; ++j) {
                float bv = w[half][j];
                int bi = 0;
#pragma unroll
                for (int c = 1; c < 8; ++c) {
                    float x = w[2 * c + half][j];
                    bool g = x > bv;
                    bv = g ? x : bv;
                    bi = g ? c : bi;
                }
                pk |= (unsigned long long)bi << (8 * (half * 4 + j));
                s += bi * bi;
            }
        }
        *(unsigned long long*)(tyb + p) = pk;
#pragma unroll
        for (int o = 32; o > 0; o >>= 1) s += __shfl_xor(s, o, 64);
        if (l == 0) y2[row] = s;
    }
}

// ---------------- 64x64-tile i8-MFMA distance kernel + fused last-block final --------
// K=64 i8 MFMA: half the VMEM bytes and half the MFMA count of the bf16 version.
// A and B fragments use identical per-lane addressing (row r, bytes lg*16..+15), so
// any k-permutation in the HW fragment layout cancels in the dot product; C layout
// is shape-determined (col=lane&15, row=(lane>>4)*4+reg — dtype-independent, HW-
// verified). d2 = x2[i]+y2[j]-2*dot is an exact non-negative integer (no clamp).
// Last block (counter==511 after threadfence'd atomicMins) reduces to the scalar.
__global__ __launch_bounds__(256) void hd_dist(const unsigned char* __restrict__ lxb,
                                               const unsigned char* __restrict__ tyb,
                                               const int* __restrict__ x2,
                                               const int* __restrict__ y2,
                                               int* __restrict__ rowmin,
                                               int* __restrict__ colmin,
                                               int* __restrict__ counter,
                                               float* __restrict__ out) {
    int b = blockIdx.y;
    int ti = blockIdx.x >> 3, tj = blockIdx.x & 7;
    int tid = threadIdx.x;
    int l = tid & 63;
    int wv = tid >> 6;
    int wr = wv >> 1, wc = wv & 1;
    int lr = l & 15, lg = l >> 4;

    const unsigned char* X = lxb + b * HWSZ + (ti * 64 + wr * 32 + lr) * 512 + lg * 16;
    const unsigned char* Y = tyb + b * HWSZ + (tj * 64 + wc * 32 + lr) * 512 + lg * 16;

    i32x4 acc00 = {0, 0, 0, 0};
    i32x4 acc01 = {0, 0, 0, 0};
    i32x4 acc10 = {0, 0, 0, 0};
    i32x4 acc11 = {0, 0, 0, 0};

#pragma unroll
    for (int kk = 0; kk < 512; kk += 64) {
        i32x4 a0 = *(const i32x4*)(X + kk);
        i32x4 a1 = *(const i32x4*)(X + 8192 + kk);   // +16 rows (512 B/row)
        i32x4 b0 = *(const i32x4*)(Y + kk);
        i32x4 b1 = *(const i32x4*)(Y + 8192 + kk);
        acc00 = __builtin_amdgcn_mfma_i32_16x16x64_i8(a0, b0, acc00, 0, 0, 0);
        acc01 = __builtin_amdgcn_mfma_i32_16x16x64_i8(a0, b1, acc01, 0, 0, 0);
        acc10 = __builtin_amdgcn_mfma_i32_16x16x64_i8(a1, b0, acc10, 0, 0, 0);
        acc11 = __builtin_amdgcn_mfma_i32_16x16x64_i8(a1, b1, acc11, 0, 0, 0);
    }

    int rb = (b << 9) + ti * 64 + wr * 32;
    int cb = (b << 9) + tj * 64 + wc * 32;
    int x2v0[4], x2v1[4];
#pragma unroll
    for (int r = 0; r < 4; ++r) {
        x2v0[r] = x2[rb + lg * 4 + r];
        x2v1[r] = x2[rb + 16 + lg * 4 + r];
    }
    int y2v0 = y2[cb + lr];
    int y2v1 = y2[cb + 16 + lr];

    int d2[2][2][4];
#pragma unroll
    for (int r = 0; r < 4; ++r) {
        d2[0][0][r] = x2v0[r] + y2v0 - 2 * acc00[r];
        d2[0][1][r] = x2v0[r] + y2v1 - 2 * acc01[r];
        d2[1][0][r] = x2v1[r] + y2v0 - 2 * acc10[r];
        d2[1][1][r] = x2v1[r] + y2v1 - 2 * acc11[r];
    }

    // row mins: row r held by 16 lanes sharing lg (C layout: col = l&15)
#pragma unroll
    for (int fi = 0; fi < 2; ++fi) {
#pragma unroll
        for (int r = 0; r < 4; ++r) {
            int m = min(d2[fi][0][r], d2[fi][1][r]);
            m = min(m, __shfl_xor(m, 1, 64));
            m = min(m, __shfl_xor(m, 2, 64));
            m = min(m, __shfl_xor(m, 4, 64));
            m = min(m, __shfl_xor(m, 8, 64));
            if (lr == 0) atomicMin(&rowmin[rb + fi * 16 + lg * 4 + r], m);
        }
    }
    // col mins
#pragma unroll
    for (int fj = 0; fj < 2; ++fj) {
        int m;
        if (fj == 0) {
            m = min(min(min(d2[0][0][0], d2[0][0][1]), min(d2[0][0][2], d2[0][0][3])),
                    min(min(d2[1][0][0], d2[1][0][1]), min(d2[1][0][2], d2[1][0][3])));
        } else {
            m = min(min(min(d2[0][1][0], d2[0][1][1]), min(d2[0][1][2], d2[0][1][3])),
                    min(min(d2[1][1][0], d2[1][1][1]), min(d2[1][1][2], d2[1][1][3])));
        }
        m = min(m, __shfl_xor(m, 16, 64));
        m = min(m, __shfl_xor(m, 32, 64));
        if (lg == 0) atomicMin(&colmin[cb + fj * 16 + lr], m);
    }

    // ---- fused final: last block reduces (rowmin ∪ colmin) -> mean of sqrt ----
    __threadfence();                       // publish this block's mins
    __shared__ int islast;
    if (tid == 0) islast = (atomicAdd(counter, 1) == 511);
    __syncthreads();
    if (islast) {
        __threadfence();                   // acquire all 511 other blocks' mins
        int bt = tid >> 5;                 // batch 0..7 (32 threads each)
        int q = tid & 31;
        int m = 0;
#pragma unroll
        for (int j = 0; j < 512; j += 32) {
            m = max(m, rowmin[(bt << 9) + j + q]);
            m = max(m, colmin[(bt << 9) + j + q]);
        }
        m = max(m, __shfl_xor(m, 1, 64));
        m = max(m, __shfl_xor(m, 2, 64));
        m = max(m, __shfl_xor(m, 4, 64));
        m = max(m, __shfl_xor(m, 8, 64));
        m = max(m, __shfl_xor(m, 16, 64));
        __shared__ float hd[8];
        if (q == 0) hd[bt] = sqrtf((float)m);
        __syncthreads();
        if (tid == 0) {
            float s = 0.0f;
#pragma unroll
            for (int i = 0; i < 8; ++i) s += hd[i];
            out[0] = s * 0.125f;
        }
    }
}

extern "C" void kernel_launch(void* const* d_in, const int* in_sizes, int n_in,
                              void* d_out, int out_size, void* d_ws, size_t ws_size,
                              hipStream_t stream) {
    (void)in_sizes; (void)n_in; (void)out_size; (void)ws_size;
    const float* logits = (const float*)d_in[0];
    const float* target = (const float*)d_in[1];

    char* ws = (char*)d_ws;
    unsigned char* lxb = (unsigned char*)ws;            // 2 MB u8 labels
    unsigned char* tyb = (unsigned char*)(ws + (2u << 20));  // 2 MB
    int* x2     = (int*)(ws + (4u << 20));              // 4096 i32
    int* y2     = x2 + 4096;                            // 4096 i32
    int* rowmin = y2 + 4096;                            // 4096 i32
    int* colmin = rowmin + 4096;                        // 4096 i32
    int* counter = colmin + 4096;                       // 1 i32
    float* out  = (float*)d_out;

    hipLaunchKernelGGL(hd_argmax, dim3(1024),  dim3(256), 0, stream,
                       logits, target, lxb, tyb, x2, y2, rowmin, colmin, counter);
    hipLaunchKernelGGL(hd_dist,   dim3(64, 8), dim3(256), 0, stream,
                       lxb, tyb, x2, y2, rowmin, colmin, counter, out);
}

// Round 11
// 42.089 us; speedup vs baseline: 1.6794x; 1.6794x over previous
//
#include <hip/hip_runtime.h>
#include <climits>

// Problem constants: B=8, C=8, H=512, W=512
#define HWSZ 262144      // H*W
#define CHWSZ 2097152    // C*H*W

typedef int i32x4 __attribute__((ext_vector_type(4)));     // i8 MFMA frag / acc
typedef float f4 __attribute__((ext_vector_type(4)));      // component-indexable float4

// ---------------- argmax: cached loads, u8 labels, i32 row-norms, min-init ----------
// Ledger (R1-R10): beyond-local-L2 read service caps ~3.2 TB/s (HBM or L3, any
// structure; NT reaches 3.4 but poisons downstream +21us). 128 MB irreducible
// input read -> ~40us floor; replay argmax = 41.5-45us = ~90-96% of floor.
// Labels int8 (0..7): distance math exact in i32; dist bytes halved vs bf16.
__global__ __launch_bounds__(256) void hd_argmax(const float* __restrict__ logits,
                                                 const float* __restrict__ target,
                                                 unsigned char* __restrict__ lxb,
                                                 unsigned char* __restrict__ tyb,
                                                 int* __restrict__ x2,
                                                 int* __restrict__ y2,
                                                 int* __restrict__ rowmin,
                                                 int* __restrict__ colmin) {
    int gid = blockIdx.x * 256 + threadIdx.x;
    if (gid < 4096) {            // fused init (dist runs later on the same stream)
        rowmin[gid] = INT_MAX;
        colmin[gid] = INT_MAX;
    }
    int t = gid;                              // 0 .. 256K-1
    int p = t << 3;                           // pixel index (8 px per thread)
    int b = p >> 18;                          // / (H*W)
    int off = p & (HWSZ - 1);
    int l = threadIdx.x & 63;
    int row = p >> 9;                         // global row 0..4095 (same for whole wave)

    const f4* L = (const f4*)(logits + (size_t)b * CHWSZ + off);
    const f4* T = (const f4*)(target + (size_t)b * CHWSZ + off);

    // ---- logits ----
    {
        f4 v[16];
#pragma unroll
        for (int c = 0; c < 8; ++c) {
            v[2 * c]     = L[c * (HWSZ / 4)];
            v[2 * c + 1] = L[c * (HWSZ / 4) + 1];
        }
        unsigned long long pk = 0;
        int s = 0;
#pragma unroll
        for (int half = 0; half < 2; ++half) {
#pragma unroll
            for (int j = 0; j < 4; ++j) {
                float bv = v[half][j];
                int bi = 0;
#pragma unroll
                for (int c = 1; c < 8; ++c) {
                    float x = v[2 * c + half][j];
                    bool g = x > bv;            // strict >: first-max, matches jnp.argmax
                    bv = g ? x : bv;
                    bi = g ? c : bi;
                }
                pk |= (unsigned long long)bi << (8 * (half * 4 + j));
                s += bi * bi;
            }
        }
        *(unsigned long long*)(lxb + p) = pk;   // 8 px -> 8 bytes
#pragma unroll
        for (int o = 32; o > 0; o >>= 1) s += __shfl_xor(s, o, 64);
        if (l == 0) x2[row] = s;
    }
    // ---- target ----
    {
        f4 w[16];
#pragma unroll
        for (int c = 0; c < 8; ++c) {
            w[2 * c]     = T[c * (HWSZ / 4)];
            w[2 * c + 1] = T[c * (HWSZ / 4) + 1];
        }
        unsigned long long pk = 0;
        int s = 0;
#pragma unroll
        for (int half = 0; half < 2; ++half) {
#pragma unroll
            for (int j = 0; j < 4; ++j) {
                float bv = w[half][j];
                int bi = 0;
#pragma unroll
                for (int c = 1; c < 8; ++c) {
                    float x = w[2 * c + half][j];
                    bool g = x > bv;
                    bv = g ? x : bv;
                    bi = g ? c : bi;
                }
                pk |= (unsigned long long)bi << (8 * (half * 4 + j));
                s += bi * bi;
            }
        }
        *(unsigned long long*)(tyb + p) = pk;
#pragma unroll
        for (int o = 32; o > 0; o >>= 1) s += __shfl_xor(s, o, 64);
        if (l == 0) y2[row] = s;
    }
}

// ---------------- 64x64-tile i8-MFMA distance kernel (no fence/counter!) ------------
// R10 lesson: per-block __threadfence (device scope) on non-coherent XCD L2s =
// serialized L2 flush storm -> dist 3us -> 42us. Kernel-boundary coherence is free;
// keep the separate 1us hd_final launch.
// K=64 i8 MFMA: half the bytes/MFMAs of bf16. A/B use identical per-lane addressing
// so k-permutations cancel; C layout is shape-determined (col=lane&15,
// row=(lane>>4)*4+reg, dtype-independent, HW-verified).
// d2 = x2[i]+y2[j]-2*dot: exact non-negative integer.
__global__ __launch_bounds__(256) void hd_dist(const unsigned char* __restrict__ lxb,
                                               const unsigned char* __restrict__ tyb,
                                               const int* __restrict__ x2,
                                               const int* __restrict__ y2,
                                               int* __restrict__ rowmin,
                                               int* __restrict__ colmin) {
    int b = blockIdx.y;
    int ti = blockIdx.x >> 3, tj = blockIdx.x & 7;
    int tid = threadIdx.x;
    int l = tid & 63;
    int wv = tid >> 6;
    int wr = wv >> 1, wc = wv & 1;
    int lr = l & 15, lg = l >> 4;

    const unsigned char* X = lxb + b * HWSZ + (ti * 64 + wr * 32 + lr) * 512 + lg * 16;
    const unsigned char* Y = tyb + b * HWSZ + (tj * 64 + wc * 32 + lr) * 512 + lg * 16;

    i32x4 acc00 = {0, 0, 0, 0};
    i32x4 acc01 = {0, 0, 0, 0};
    i32x4 acc10 = {0, 0, 0, 0};
    i32x4 acc11 = {0, 0, 0, 0};

#pragma unroll
    for (int kk = 0; kk < 512; kk += 64) {
        i32x4 a0 = *(const i32x4*)(X + kk);
        i32x4 a1 = *(const i32x4*)(X + 8192 + kk);   // +16 rows (512 B/row)
        i32x4 b0 = *(const i32x4*)(Y + kk);
        i32x4 b1 = *(const i32x4*)(Y + 8192 + kk);
        acc00 = __builtin_amdgcn_mfma_i32_16x16x64_i8(a0, b0, acc00, 0, 0, 0);
        acc01 = __builtin_amdgcn_mfma_i32_16x16x64_i8(a0, b1, acc01, 0, 0, 0);
        acc10 = __builtin_amdgcn_mfma_i32_16x16x64_i8(a1, b0, acc10, 0, 0, 0);
        acc11 = __builtin_amdgcn_mfma_i32_16x16x64_i8(a1, b1, acc11, 0, 0, 0);
    }

    int rb = (b << 9) + ti * 64 + wr * 32;
    int cb = (b << 9) + tj * 64 + wc * 32;
    int x2v0[4], x2v1[4];
#pragma unroll
    for (int r = 0; r < 4; ++r) {
        x2v0[r] = x2[rb + lg * 4 + r];
        x2v1[r] = x2[rb + 16 + lg * 4 + r];
    }
    int y2v0 = y2[cb + lr];
    int y2v1 = y2[cb + 16 + lr];

    int d2[2][2][4];
#pragma unroll
    for (int r = 0; r < 4; ++r) {
        d2[0][0][r] = x2v0[r] + y2v0 - 2 * acc00[r];
        d2[0][1][r] = x2v0[r] + y2v1 - 2 * acc01[r];
        d2[1][0][r] = x2v1[r] + y2v0 - 2 * acc10[r];
        d2[1][1][r] = x2v1[r] + y2v1 - 2 * acc11[r];
    }

    // row mins: row r held by 16 lanes sharing lg (C layout: col = l&15)
#pragma unroll
    for (int fi = 0; fi < 2; ++fi) {
#pragma unroll
        for (int r = 0; r < 4; ++r) {
            int m = min(d2[fi][0][r], d2[fi][1][r]);
            m = min(m, __shfl_xor(m, 1, 64));
            m = min(m, __shfl_xor(m, 2, 64));
            m = min(m, __shfl_xor(m, 4, 64));
            m = min(m, __shfl_xor(m, 8, 64));
            if (lr == 0) atomicMin(&rowmin[rb + fi * 16 + lg * 4 + r], m);
        }
    }
    // col mins
#pragma unroll
    for (int fj = 0; fj < 2; ++fj) {
        int m;
        if (fj == 0) {
            m = min(min(min(d2[0][0][0], d2[0][0][1]), min(d2[0][0][2], d2[0][0][3])),
                    min(min(d2[1][0][0], d2[1][0][1]), min(d2[1][0][2], d2[1][0][3])));
        } else {
            m = min(min(min(d2[0][1][0], d2[0][1][1]), min(d2[0][1][2], d2[0][1][3])),
                    min(min(d2[1][1][0], d2[1][1][1]), min(d2[1][1][2], d2[1][1][3])));
        }
        m = min(m, __shfl_xor(m, 16, 64));
        m = min(m, __shfl_xor(m, 32, 64));
        if (lg == 0) atomicMin(&colmin[cb + fj * 16 + lr], m);
    }
}

// ---------------- final: per-batch max over (rowmin ∪ colmin), sqrt, mean ----------------
__global__ __launch_bounds__(512) void hd_final(const int* __restrict__ rowmin,
                                                const int* __restrict__ colmin,
                                                float* __restrict__ out) {
    int w = threadIdx.x >> 6, l = threadIdx.x & 63;   // wave w = batch w
    int m = 0;
#pragma unroll
    for (int j = 0; j < 512; j += 64) {
        m = max(m, rowmin[(w << 9) + j + l]);
        m = max(m, colmin[(w << 9) + j + l]);
    }
#pragma unroll
    for (int s = 32; s > 0; s >>= 1) m = max(m, __shfl_xor(m, s, 64));
    __shared__ float hd[8];
    if (l == 0) hd[w] = sqrtf((float)m);
    __syncthreads();
    if (threadIdx.x == 0) {
        float s = 0.0f;
#pragma unroll
        for (int i = 0; i < 8; ++i) s += hd[i];
        out[0] = s * 0.125f;
    }
}

extern "C" void kernel_launch(void* const* d_in, const int* in_sizes, int n_in,
                              void* d_out, int out_size, void* d_ws, size_t ws_size,
                              hipStream_t stream) {
    (void)in_sizes; (void)n_in; (void)out_size; (void)ws_size;
    const float* logits = (const float*)d_in[0];
    const float* target = (const float*)d_in[1];

    char* ws = (char*)d_ws;
    unsigned char* lxb = (unsigned char*)ws;                 // 2 MB u8 labels
    unsigned char* tyb = (unsigned char*)(ws + (2u << 20));  // 2 MB
    int* x2     = (int*)(ws + (4u << 20));              // 4096 i32
    int* y2     = x2 + 4096;                            // 4096 i32
    int* rowmin = y2 + 4096;                            // 4096 i32
    int* colmin = rowmin + 4096;                        // 4096 i32
    float* out  = (float*)d_out;

    hipLaunchKernelGGL(hd_argmax, dim3(1024),  dim3(256), 0, stream,
                       logits, target, lxb, tyb, x2, y2, rowmin, colmin);
    hipLaunchKernelGGL(hd_dist,   dim3(64, 8), dim3(256), 0, stream,
                       lxb, tyb, x2, y2, rowmin, colmin);
    hipLaunchKernelGGL(hd_final,  dim3(1),     dim3(512), 0, stream, rowmin, colmin, out);
}